// Round 5
// baseline (1743.322 us; speedup 1.0000x reference)
//
#include <hip/hip_runtime.h>
#include <hip/hip_bf16.h>

// GCN: 3x GCNConv(H=64) + global mean pool + linear head.
// Round 4 -> 5: source-chunked gather (16 chunks x 1.6MB => per-XCD-L2-resident
// sources), per-(dst,chunk) CSR segments, LDS row accumulators (49 rows/block,
// all 2041 blocks resident). Separate register-tiled GEMM kernels (4x4/thread,
// float4 LDS reads) instead of the LDS-issue-bound inline GEMM.

#define WS_ALIGN(x) (((x) + 255) & ~size_t(255))
#define NCHUNK 16
#define NB 49          // dst rows per gather block

// zero cnt16/cursor16 (n16 entries) and pool accumulators
__global__ __launch_bounds__(256) void k_init0(int n16, int g, int* cnt, int* cursor,
                                               float* gsum, float* gcnt) {
    int i = blockIdx.x * blockDim.x + threadIdx.x;
    if (i < n16) { cnt[i] = 0; cursor[i] = 0; }
    if (i < g) { gsum[i] = 0.f; gcnt[i] = 0.f; }
}

// count per (dst, src-chunk) bin
__global__ __launch_bounds__(256) void k_cnt(int e, int sc, const int* __restrict__ src,
                                             const int* __restrict__ dst,
                                             int* __restrict__ cnt) {
    int i = blockIdx.x * blockDim.x + threadIdx.x;
    if (i >= e) return;
    int c = src[i] / sc;
    atomicAdd(&cnt[dst[i] * NCHUNK + c], 1);
}

// scan1: 2048-elem tiles, 8 per thread; in-place capable (reads before writes)
__global__ __launch_bounds__(256) void k_scan1(int n, const int* __restrict__ in,
                                               int* __restrict__ outx,
                                               int* __restrict__ psum) {
    __shared__ int sd[256];
    int tid = threadIdx.x;
    int i0 = blockIdx.x * 2048 + tid * 8;
    int a[8]; int tsum = 0;
#pragma unroll
    for (int q = 0; q < 8; ++q) { a[q] = (i0 + q < n) ? in[i0 + q] : 0; tsum += a[q]; }
    sd[tid] = tsum;
    __syncthreads();
    for (int off = 1; off < 256; off <<= 1) {
        int v = (tid >= off) ? sd[tid - off] : 0;
        __syncthreads();
        sd[tid] += v;
        __syncthreads();
    }
    int excl = sd[tid] - tsum;
#pragma unroll
    for (int q = 0; q < 8; ++q) { if (i0 + q < n) outx[i0 + q] = excl; excl += a[q]; }
    if (tid == 255) psum[blockIdx.x] = sd[255];
}

__global__ __launch_bounds__(256) void k_scan2(int nchunks, int* __restrict__ psum) {
    __shared__ int sd[256];
    int tid = threadIdx.x;
    int i0 = tid * 4;
    int a = (i0 + 0 < nchunks) ? psum[i0 + 0] : 0;
    int b = (i0 + 1 < nchunks) ? psum[i0 + 1] : 0;
    int c = (i0 + 2 < nchunks) ? psum[i0 + 2] : 0;
    int d = (i0 + 3 < nchunks) ? psum[i0 + 3] : 0;
    int tsum = a + b + c + d;
    sd[tid] = tsum;
    __syncthreads();
    for (int off = 1; off < 256; off <<= 1) {
        int v = (tid >= off) ? sd[tid - off] : 0;
        __syncthreads();
        sd[tid] += v;
        __syncthreads();
    }
    int excl = sd[tid] - tsum;
    if (i0 + 0 < nchunks) psum[i0 + 0] = excl;
    if (i0 + 1 < nchunks) psum[i0 + 1] = excl + a;
    if (i0 + 2 < nchunks) psum[i0 + 2] = excl + a + b;
    if (i0 + 3 < nchunks) psum[i0 + 3] = excl + a + b + c;
}

__global__ __launch_bounds__(256) void k_scan3(int n, int e, int* __restrict__ outx,
                                               const int* __restrict__ psum) {
    int i = blockIdx.x * blockDim.x + threadIdx.x;
    if (i < n) outx[i] += psum[i >> 11];
    if (i == n) outx[n] = e;
}

// dinv from starts16 row sums (+1 self-loop); xs = x*dinv
__global__ __launch_bounds__(256) void k_dinv(int n, const int* __restrict__ starts,
                                              const float* __restrict__ x,
                                              float* __restrict__ dinv,
                                              float* __restrict__ xs) {
    int i = blockIdx.x * blockDim.x + threadIdx.x;
    if (i >= n) return;
    int deg = starts[(i + 1) * NCHUNK] - starts[i * NCHUNK] + 1;
    float di = 1.0f / sqrtf((float)deg);
    dinv[i] = di;
    xs[i] = x[i] * di;
}

__global__ __launch_bounds__(256) void k_scatter(int e, int sc, const int* __restrict__ src,
                                                 const int* __restrict__ dst,
                                                 const int* __restrict__ starts,
                                                 int* __restrict__ cursor,
                                                 int* __restrict__ csr) {
    int i = blockIdx.x * blockDim.x + threadIdx.x;
    if (i >= e) return;
    int u = src[i];
    int bin = dst[i] * NCHUNK + u / sc;
    int pos = starts[bin] + atomicAdd(&cursor[bin], 1);
    csr[pos] = u;
}

// layer 1 fused (rank-1): hs1[v][j] = relu(((sum xs[u] + xs[v])*dinv)*w1[j]+b1[j])*dinv
__global__ __launch_bounds__(256, 8) void k_layer1(int n, const int* __restrict__ starts,
                                                   const int* __restrict__ csr,
                                                   const float* __restrict__ xs,
                                                   const float* __restrict__ dinv,
                                                   const float* __restrict__ w1,
                                                   const float* __restrict__ b1,
                                                   float* __restrict__ hs_out) {
    int tid = threadIdx.x;
    int r = tid >> 6, lane = tid & 63;
    float w1r = w1[lane], b1r = b1[lane];
    int wid = blockIdx.x * 4 + r;
    int stride = gridDim.x * 4;
    for (int v = wid; v < n; v += stride) {
        int s0 = starts[v * NCHUNK], s1 = starts[(v + 1) * NCHUNK];
        float acc = 0.f;
        for (int k = s0 + lane; k < s1; k += 64) acc += xs[csr[k]];
#pragma unroll
        for (int m = 32; m > 0; m >>= 1) acc += __shfl_xor(acc, m, 64);
        float dv = dinv[v];
        float s = (acc + xs[v]) * dv;
        hs_out[(size_t)v * 64 + lane] = fmaxf(s * w1r + b1r, 0.f) * dv;
    }
}

// chunked gather: block owns NB dst rows in LDS; chunk-major loop keeps the
// 1.6MB source slice L2-resident. agg[v] = (sum_in hs[u] + hs[v]) * dinv[v].
__global__ __launch_bounds__(256, 8) void k_gather_c(int n, const int* __restrict__ starts,
                                                     const int* __restrict__ csr,
                                                     const float* __restrict__ hs_in,
                                                     const float* __restrict__ dinv,
                                                     float* __restrict__ agg) {
    __shared__ float accL[NB * 64];
    int tid = threadIdx.x, r = tid >> 6, lane = tid & 63;
    int v0 = blockIdx.x * NB;
    int nb = n - v0; if (nb > NB) nb = NB;
    if (nb <= 0) return;
    for (int vi = r; vi < nb; vi += 4)
        accL[vi * 64 + lane] = hs_in[(size_t)(v0 + vi) * 64 + lane];   // self-loop
    for (int c = 0; c < NCHUNK; ++c) {
        for (int vi = r; vi < nb; vi += 4) {
            int v = v0 + vi;
            int b0 = starts[v * NCHUNK + c], b1 = starts[v * NCHUNK + c + 1];
            if (b0 == b1) continue;
            float a0 = 0.f, a1 = 0.f, a2 = 0.f, a3 = 0.f;
            for (int base = b0; base < b1; base += 64) {
                int k = base + lane;
                int u = (k < b1) ? csr[k] : 0;
                int m = b1 - base; if (m > 64) m = 64;
                int t = 0;
                for (; t + 4 <= m; t += 4) {
                    int u0 = __shfl(u, t, 64),     u1 = __shfl(u, t + 1, 64);
                    int u2 = __shfl(u, t + 2, 64), u3 = __shfl(u, t + 3, 64);
                    a0 += hs_in[(size_t)u0 * 64 + lane];
                    a1 += hs_in[(size_t)u1 * 64 + lane];
                    a2 += hs_in[(size_t)u2 * 64 + lane];
                    a3 += hs_in[(size_t)u3 * 64 + lane];
                }
                for (; t < m; ++t) {
                    int u0 = __shfl(u, t, 64);
                    a0 += hs_in[(size_t)u0 * 64 + lane];
                }
            }
            accL[vi * 64 + lane] += (a0 + a1) + (a2 + a3);
        }
        __syncthreads();   // block-level chunk phase alignment (uniform)
    }
    for (int vi = r; vi < nb; vi += 4) {
        int v = v0 + vi;
        agg[(size_t)v * 64 + lane] = accL[vi * 64 + lane] * dinv[v];
    }
}

// register-tiled GEMM: 64-node tile/block, thread = (ng,jg) computes 4 nodes x 4 j.
// hs_out = relu(agg @ w + b) * dinv
__global__ __launch_bounds__(256, 4) void k_gemm_mid(int n, const float* __restrict__ agg,
                                                     const float* __restrict__ w,
                                                     const float* __restrict__ b,
                                                     const float* __restrict__ dinv,
                                                     float* __restrict__ hs_out) {
    __shared__ float4 wsL[1024];       // [k][jg]
    __shared__ float rowsT[64 * 68];   // [k][node], padded stride 68
    int tid = threadIdx.x;
    const float4* w4 = (const float4*)w;
    for (int i = tid; i < 1024; i += 256) wsL[i] = w4[i];
    int wv = tid >> 6, lane = tid & 63;
    int tile0 = blockIdx.x * 64;
#pragma unroll
    for (int rr = 0; rr < 16; ++rr) {
        int nloc = wv * 16 + rr;
        int nn = tile0 + nloc;
        float val = (nn < n) ? agg[(size_t)nn * 64 + lane] : 0.f;
        rowsT[lane * 68 + nloc] = val;
    }
    __syncthreads();
    int ng = tid >> 4, jg = tid & 15;
    float4 bv = ((const float4*)b)[jg];
    float4 acc[4] = {bv, bv, bv, bv};
#pragma unroll
    for (int k = 0; k < 64; ++k) {
        float4 wk = wsL[k * 16 + jg];
        float4 rv = *(const float4*)&rowsT[k * 68 + ng * 4];
        acc[0].x += rv.x * wk.x; acc[0].y += rv.x * wk.y; acc[0].z += rv.x * wk.z; acc[0].w += rv.x * wk.w;
        acc[1].x += rv.y * wk.x; acc[1].y += rv.y * wk.y; acc[1].z += rv.y * wk.z; acc[1].w += rv.y * wk.w;
        acc[2].x += rv.z * wk.x; acc[2].y += rv.z * wk.y; acc[2].z += rv.z * wk.z; acc[2].w += rv.z * wk.w;
        acc[3].x += rv.w * wk.x; acc[3].y += rv.w * wk.y; acc[3].z += rv.w * wk.z; acc[3].w += rv.w * wk.w;
    }
    float4* out4 = (float4*)hs_out;
#pragma unroll
    for (int i = 0; i < 4; ++i) {
        int nn = tile0 + ng * 4 + i;
        if (nn < n) {
            float dv = dinv[nn];
            float4 o;
            o.x = fmaxf(acc[i].x, 0.f) * dv;
            o.y = fmaxf(acc[i].y, 0.f) * dv;
            o.z = fmaxf(acc[i].z, 0.f) * dv;
            o.w = fmaxf(acc[i].w, 0.f) * dv;
            out4[(size_t)nn * 16 + jg] = o;
        }
    }
}

// final GEMM: relu(agg @ w3 + b3) . fcw -> dots[v]
__global__ __launch_bounds__(256, 4) void k_gemm_final(int n, const float* __restrict__ agg,
                                                       const float* __restrict__ w,
                                                       const float* __restrict__ b,
                                                       const float* __restrict__ fcw,
                                                       float* __restrict__ dots) {
    __shared__ float4 wsL[1024];
    __shared__ float rowsT[64 * 68];
    int tid = threadIdx.x;
    const float4* w4 = (const float4*)w;
    for (int i = tid; i < 1024; i += 256) wsL[i] = w4[i];
    int wv = tid >> 6, lane = tid & 63;
    int tile0 = blockIdx.x * 64;
#pragma unroll
    for (int rr = 0; rr < 16; ++rr) {
        int nloc = wv * 16 + rr;
        int nn = tile0 + nloc;
        float val = (nn < n) ? agg[(size_t)nn * 64 + lane] : 0.f;
        rowsT[lane * 68 + nloc] = val;
    }
    __syncthreads();
    int ng = tid >> 4, jg = tid & 15;
    float4 bv = ((const float4*)b)[jg];
    float4 acc[4] = {bv, bv, bv, bv};
#pragma unroll
    for (int k = 0; k < 64; ++k) {
        float4 wk = wsL[k * 16 + jg];
        float4 rv = *(const float4*)&rowsT[k * 68 + ng * 4];
        acc[0].x += rv.x * wk.x; acc[0].y += rv.x * wk.y; acc[0].z += rv.x * wk.z; acc[0].w += rv.x * wk.w;
        acc[1].x += rv.y * wk.x; acc[1].y += rv.y * wk.y; acc[1].z += rv.y * wk.z; acc[1].w += rv.y * wk.w;
        acc[2].x += rv.z * wk.x; acc[2].y += rv.z * wk.y; acc[2].z += rv.z * wk.z; acc[2].w += rv.z * wk.w;
        acc[3].x += rv.w * wk.x; acc[3].y += rv.w * wk.y; acc[3].z += rv.w * wk.z; acc[3].w += rv.w * wk.w;
    }
    float4 fv = ((const float4*)fcw)[jg];
    float dp[4];
#pragma unroll
    for (int i = 0; i < 4; ++i) {
        dp[i] = fmaxf(acc[i].x, 0.f) * fv.x + fmaxf(acc[i].y, 0.f) * fv.y
              + fmaxf(acc[i].z, 0.f) * fv.z + fmaxf(acc[i].w, 0.f) * fv.w;
#pragma unroll
        for (int off = 8; off > 0; off >>= 1) dp[i] += __shfl_xor(dp[i], off, 64);
    }
    if (jg == 0) {
#pragma unroll
        for (int i = 0; i < 4; ++i) {
            int nn = tile0 + ng * 4 + i;
            if (nn < n) dots[nn] = dp[i];
        }
    }
}

// pooled accumulation: LDS-binned segmented reduce over sorted batch.
__global__ __launch_bounds__(256) void k_pool(int n, const float* __restrict__ dots,
                                              const int* __restrict__ batch,
                                              float* __restrict__ gsum,
                                              float* __restrict__ gcnt) {
    __shared__ float ls[64], lc[64];
    __shared__ int gmin_s;
    int tid = threadIdx.x;
    int i0 = blockIdx.x * 1024;
    if (tid == 0) gmin_s = batch[i0];
    if (tid < 64) { ls[tid] = 0.f; lc[tid] = 0.f; }
    __syncthreads();
    int gmin = gmin_s;
#pragma unroll
    for (int c = 0; c < 4; ++c) {
        int i = i0 + c * 256 + tid;
        if (i < n) {
            int g = batch[i];
            float d = dots[i];
            int rr = g - gmin;
            if (rr < 64) {
                atomicAdd(&ls[rr], d);
                atomicAdd(&lc[rr], 1.f);
            } else {
                atomicAdd(&gsum[g], d);
                atomicAdd(&gcnt[g], 1.f);
            }
        }
    }
    __syncthreads();
    if (tid < 64 && lc[tid] != 0.f) {
        atomicAdd(&gsum[gmin + tid], ls[tid]);
        atomicAdd(&gcnt[gmin + tid], lc[tid]);
    }
}

__global__ __launch_bounds__(256) void k_out(int g, const float* __restrict__ gsum,
                                             const float* __restrict__ gcnt,
                                             const float* __restrict__ fcb,
                                             float* __restrict__ out) {
    int i = blockIdx.x * blockDim.x + threadIdx.x;
    if (i < g) out[i] = gsum[i] / fmaxf(gcnt[i], 1.f) + fcb[0];
}

extern "C" void kernel_launch(void* const* d_in, const int* in_sizes, int n_in,
                              void* d_out, int out_size, void* d_ws, size_t ws_size,
                              hipStream_t stream) {
    const float* x    = (const float*)d_in[0];
    const int*   ei   = (const int*)d_in[1];
    const int*   batch= (const int*)d_in[2];
    const float* w1   = (const float*)d_in[3];
    const float* b1   = (const float*)d_in[4];
    const float* w2   = (const float*)d_in[5];
    const float* b2   = (const float*)d_in[6];
    const float* w3   = (const float*)d_in[7];
    const float* b3   = (const float*)d_in[8];
    const float* fcw  = (const float*)d_in[9];
    const float* fcb  = (const float*)d_in[10];
    float* out = (float*)d_out;

    const int N = in_sizes[0];
    const int E = in_sizes[1] / 2;
    const int G = out_size;
    const int H = 64;
    const int SC = (N + NCHUNK - 1) / NCHUNK;   // src-chunk size
    const int n16 = N * NCHUNK;

    const int* src = ei;
    const int* dst = ei + E;

    char* p = (char*)d_ws;
    int*   starts16 = (int*)p; p += WS_ALIGN(sizeof(int) * (size_t)(n16 + 1));  // counts, scanned in place
    int*   cursor16 = (int*)p; p += WS_ALIGN(sizeof(int) * (size_t)n16);
    int*   psum     = (int*)p; p += WS_ALIGN(sizeof(int) * 1024);
    int*   csr      = (int*)p; p += WS_ALIGN(sizeof(int) * (size_t)E);
    float* dinv     = (float*)p; p += WS_ALIGN(sizeof(float) * N);
    float* xs       = (float*)p; p += WS_ALIGN(sizeof(float) * N);
    float* bufA     = (float*)p; p += WS_ALIGN(sizeof(float) * (size_t)N * H);
    float* bufB     = (float*)p; p += WS_ALIGN(sizeof(float) * (size_t)N * H);
    float* dots     = (float*)p; p += WS_ALIGN(sizeof(float) * N);
    float* gsum     = (float*)p; p += WS_ALIGN(sizeof(float) * G);
    float* gcnt     = (float*)p; p += WS_ALIGN(sizeof(float) * G);

    const int B = 256;
    int gridN    = (N + B - 1) / B;
    int gridE    = (E + B - 1) / B;
    int gridG    = (G + B - 1) / B;
    int grid16   = (n16 + B - 1) / B;
    int nscan    = (n16 + 2047) / 2048;          // scan1 blocks (<=1024)
    int gridS3   = (n16 + 1 + B - 1) / B;
    int gridGa   = (N + NB - 1) / NB;            // 2041 persistent-resident blocks
    int gridGe   = (N + 63) / 64;                // 64-node GEMM tiles
    int gridPool = (N + 1023) / 1024;
    int gridPers = 2048;
    if (gridPers * 4 > N) gridPers = (N + 3) / 4;

    k_init0<<<grid16, B, 0, stream>>>(n16, G, starts16, cursor16, gsum, gcnt);
    k_cnt<<<gridE, B, 0, stream>>>(E, SC, src, dst, starts16);
    k_scan1<<<nscan, B, 0, stream>>>(n16, starts16, starts16, psum);
    k_scan2<<<1, B, 0, stream>>>(nscan, psum);
    k_scan3<<<gridS3, B, 0, stream>>>(n16, E, starts16, psum);
    k_dinv<<<gridN, B, 0, stream>>>(N, starts16, x, dinv, xs);
    k_scatter<<<gridE, B, 0, stream>>>(E, SC, src, dst, starts16, cursor16, csr);
    // layer 1 (rank-1, fused)
    k_layer1<<<gridPers, B, 0, stream>>>(N, starts16, csr, xs, dinv, w1, b1, bufA);
    // layer 2
    k_gather_c<<<gridGa, B, 0, stream>>>(N, starts16, csr, bufA, dinv, bufB);
    k_gemm_mid<<<gridGe, B, 0, stream>>>(N, bufB, w2, b2, dinv, bufA);
    // layer 3
    k_gather_c<<<gridGa, B, 0, stream>>>(N, starts16, csr, bufA, dinv, bufB);
    k_gemm_final<<<gridGe, B, 0, stream>>>(N, bufB, w3, b3, fcw, dots);
    // pooling + head
    k_pool<<<gridPool, B, 0, stream>>>(N, dots, batch, gsum, gcnt);
    k_out<<<gridG, B, 0, stream>>>(G, gsum, gcnt, fcb, out);
}

// Round 6
// 1062.027 us; speedup vs baseline: 1.6415x; 1.6415x over previous
//
#include <hip/hip_runtime.h>
#include <hip/hip_bf16.h>

// GCN: 3x GCNConv(H=64) + global mean pool + linear head.
// Round 5 -> 6: keep chunked-CSR gather (worked); replace the broken tiled
// GEMM (2.5GB phantom traffic, 845us) with the R4-proven persistent
// wave-per-node GEMM (weights in LDS once per block, scalar conflict-free reads).

#define WS_ALIGN(x) (((x) + 255) & ~size_t(255))
#define NCHUNK 16
#define NB 49          // dst rows per gather block

// zero cnt16/cursor16 (n16 entries) and pool accumulators
__global__ __launch_bounds__(256) void k_init0(int n16, int g, int* cnt, int* cursor,
                                               float* gsum, float* gcnt) {
    int i = blockIdx.x * blockDim.x + threadIdx.x;
    if (i < n16) { cnt[i] = 0; cursor[i] = 0; }
    if (i < g) { gsum[i] = 0.f; gcnt[i] = 0.f; }
}

// count per (dst, src-chunk) bin
__global__ __launch_bounds__(256) void k_cnt(int e, int sc, const int* __restrict__ src,
                                             const int* __restrict__ dst,
                                             int* __restrict__ cnt) {
    int i = blockIdx.x * blockDim.x + threadIdx.x;
    if (i >= e) return;
    int c = src[i] / sc;
    atomicAdd(&cnt[dst[i] * NCHUNK + c], 1);
}

// scan1: 2048-elem tiles, 8 per thread; in-place capable (reads before writes)
__global__ __launch_bounds__(256) void k_scan1(int n, const int* __restrict__ in,
                                               int* __restrict__ outx,
                                               int* __restrict__ psum) {
    __shared__ int sd[256];
    int tid = threadIdx.x;
    int i0 = blockIdx.x * 2048 + tid * 8;
    int a[8]; int tsum = 0;
#pragma unroll
    for (int q = 0; q < 8; ++q) { a[q] = (i0 + q < n) ? in[i0 + q] : 0; tsum += a[q]; }
    sd[tid] = tsum;
    __syncthreads();
    for (int off = 1; off < 256; off <<= 1) {
        int v = (tid >= off) ? sd[tid - off] : 0;
        __syncthreads();
        sd[tid] += v;
        __syncthreads();
    }
    int excl = sd[tid] - tsum;
#pragma unroll
    for (int q = 0; q < 8; ++q) { if (i0 + q < n) outx[i0 + q] = excl; excl += a[q]; }
    if (tid == 255) psum[blockIdx.x] = sd[255];
}

__global__ __launch_bounds__(256) void k_scan2(int nchunks, int* __restrict__ psum) {
    __shared__ int sd[256];
    int tid = threadIdx.x;
    int i0 = tid * 4;
    int a = (i0 + 0 < nchunks) ? psum[i0 + 0] : 0;
    int b = (i0 + 1 < nchunks) ? psum[i0 + 1] : 0;
    int c = (i0 + 2 < nchunks) ? psum[i0 + 2] : 0;
    int d = (i0 + 3 < nchunks) ? psum[i0 + 3] : 0;
    int tsum = a + b + c + d;
    sd[tid] = tsum;
    __syncthreads();
    for (int off = 1; off < 256; off <<= 1) {
        int v = (tid >= off) ? sd[tid - off] : 0;
        __syncthreads();
        sd[tid] += v;
        __syncthreads();
    }
    int excl = sd[tid] - tsum;
    if (i0 + 0 < nchunks) psum[i0 + 0] = excl;
    if (i0 + 1 < nchunks) psum[i0 + 1] = excl + a;
    if (i0 + 2 < nchunks) psum[i0 + 2] = excl + a + b;
    if (i0 + 3 < nchunks) psum[i0 + 3] = excl + a + b + c;
}

__global__ __launch_bounds__(256) void k_scan3(int n, int e, int* __restrict__ outx,
                                               const int* __restrict__ psum) {
    int i = blockIdx.x * blockDim.x + threadIdx.x;
    if (i < n) outx[i] += psum[i >> 11];
    if (i == n) outx[n] = e;
}

// dinv from starts16 row sums (+1 self-loop); xs = x*dinv
__global__ __launch_bounds__(256) void k_dinv(int n, const int* __restrict__ starts,
                                              const float* __restrict__ x,
                                              float* __restrict__ dinv,
                                              float* __restrict__ xs) {
    int i = blockIdx.x * blockDim.x + threadIdx.x;
    if (i >= n) return;
    int deg = starts[(i + 1) * NCHUNK] - starts[i * NCHUNK] + 1;
    float di = 1.0f / sqrtf((float)deg);
    dinv[i] = di;
    xs[i] = x[i] * di;
}

__global__ __launch_bounds__(256) void k_scatter(int e, int sc, const int* __restrict__ src,
                                                 const int* __restrict__ dst,
                                                 const int* __restrict__ starts,
                                                 int* __restrict__ cursor,
                                                 int* __restrict__ csr) {
    int i = blockIdx.x * blockDim.x + threadIdx.x;
    if (i >= e) return;
    int u = src[i];
    int bin = dst[i] * NCHUNK + u / sc;
    int pos = starts[bin] + atomicAdd(&cursor[bin], 1);
    csr[pos] = u;
}

// layer 1 fused (rank-1): hs1[v][j] = relu(((sum xs[u] + xs[v])*dinv)*w1[j]+b1[j])*dinv
__global__ __launch_bounds__(256, 8) void k_layer1(int n, const int* __restrict__ starts,
                                                   const int* __restrict__ csr,
                                                   const float* __restrict__ xs,
                                                   const float* __restrict__ dinv,
                                                   const float* __restrict__ w1,
                                                   const float* __restrict__ b1,
                                                   float* __restrict__ hs_out) {
    int tid = threadIdx.x;
    int r = tid >> 6, lane = tid & 63;
    float w1r = w1[lane], b1r = b1[lane];
    int wid = blockIdx.x * 4 + r;
    int stride = gridDim.x * 4;
    for (int v = wid; v < n; v += stride) {
        int s0 = starts[v * NCHUNK], s1 = starts[(v + 1) * NCHUNK];
        float acc = 0.f;
        for (int k = s0 + lane; k < s1; k += 64) acc += xs[csr[k]];
#pragma unroll
        for (int m = 32; m > 0; m >>= 1) acc += __shfl_xor(acc, m, 64);
        float dv = dinv[v];
        float s = (acc + xs[v]) * dv;
        hs_out[(size_t)v * 64 + lane] = fmaxf(s * w1r + b1r, 0.f) * dv;
    }
}

// chunked gather: block owns NB dst rows in LDS; chunk-major loop keeps the
// 1.6MB source slice L2-resident. agg[v] = (sum_in hs[u] + hs[v]) * dinv[v].
__global__ __launch_bounds__(256, 8) void k_gather_c(int n, const int* __restrict__ starts,
                                                     const int* __restrict__ csr,
                                                     const float* __restrict__ hs_in,
                                                     const float* __restrict__ dinv,
                                                     float* __restrict__ agg) {
    __shared__ float accL[NB * 64];
    int tid = threadIdx.x, r = tid >> 6, lane = tid & 63;
    int v0 = blockIdx.x * NB;
    int nb = n - v0; if (nb > NB) nb = NB;
    if (nb <= 0) return;
    for (int vi = r; vi < nb; vi += 4)
        accL[vi * 64 + lane] = hs_in[(size_t)(v0 + vi) * 64 + lane];   // self-loop
    for (int c = 0; c < NCHUNK; ++c) {
        for (int vi = r; vi < nb; vi += 4) {
            int v = v0 + vi;
            int b0 = starts[v * NCHUNK + c], b1 = starts[v * NCHUNK + c + 1];
            if (b0 == b1) continue;
            float a0 = 0.f, a1 = 0.f, a2 = 0.f, a3 = 0.f;
            for (int base = b0; base < b1; base += 64) {
                int k = base + lane;
                int u = (k < b1) ? csr[k] : 0;
                int m = b1 - base; if (m > 64) m = 64;
                int t = 0;
                for (; t + 4 <= m; t += 4) {
                    int u0 = __shfl(u, t, 64),     u1 = __shfl(u, t + 1, 64);
                    int u2 = __shfl(u, t + 2, 64), u3 = __shfl(u, t + 3, 64);
                    a0 += hs_in[(size_t)u0 * 64 + lane];
                    a1 += hs_in[(size_t)u1 * 64 + lane];
                    a2 += hs_in[(size_t)u2 * 64 + lane];
                    a3 += hs_in[(size_t)u3 * 64 + lane];
                }
                for (; t < m; ++t) {
                    int u0 = __shfl(u, t, 64);
                    a0 += hs_in[(size_t)u0 * 64 + lane];
                }
            }
            accL[vi * 64 + lane] += (a0 + a1) + (a2 + a3);
        }
        __syncthreads();   // block-level chunk phase alignment (uniform)
    }
    for (int vi = r; vi < nb; vi += 4) {
        int v = v0 + vi;
        agg[(size_t)v * 64 + lane] = accL[vi * 64 + lane] * dinv[v];
    }
}

// persistent wave-per-node GEMM (R4-proven structure): hs_out = relu(agg@w+b)*dinv
__global__ __launch_bounds__(256, 8) void k_gemm_mid(int n, const float* __restrict__ agg,
                                                     const float* __restrict__ w,
                                                     const float* __restrict__ b,
                                                     const float* __restrict__ dinv,
                                                     float* __restrict__ hs_out) {
    __shared__ float ws[64 * 64];    // [k][j], coalesced load, conflict-free read
    __shared__ float rowl[4][64];    // per-wave row slot (wave-local use only)
    int tid = threadIdx.x;
    for (int k = tid; k < 64 * 64; k += 256) ws[k] = w[k];
    __syncthreads();
    int r = tid >> 6, lane = tid & 63;
    float breg = b[lane];
    int wid = blockIdx.x * 4 + r;
    int stride = gridDim.x * 4;
    for (int v = wid; v < n; v += stride) {
        rowl[r][lane] = agg[(size_t)v * 64 + lane];
        // wave-local RAW on LDS: ordered by lgkmcnt, no barrier needed
        float acc = breg;
#pragma unroll
        for (int k = 0; k < 64; ++k) acc += rowl[r][k] * ws[k * 64 + lane];
        hs_out[(size_t)v * 64 + lane] = fmaxf(acc, 0.f) * dinv[v];
    }
}

// persistent final GEMM: dots[v] = relu(agg@w3+b3) . fcw
__global__ __launch_bounds__(256, 8) void k_gemm_final(int n, const float* __restrict__ agg,
                                                       const float* __restrict__ w,
                                                       const float* __restrict__ b,
                                                       const float* __restrict__ fcw,
                                                       float* __restrict__ dots) {
    __shared__ float ws[64 * 64];
    __shared__ float rowl[4][64];
    int tid = threadIdx.x;
    for (int k = tid; k < 64 * 64; k += 256) ws[k] = w[k];
    __syncthreads();
    int r = tid >> 6, lane = tid & 63;
    float breg = b[lane];
    float freg = fcw[lane];
    int wid = blockIdx.x * 4 + r;
    int stride = gridDim.x * 4;
    for (int v = wid; v < n; v += stride) {
        rowl[r][lane] = agg[(size_t)v * 64 + lane];
        float acc = breg;
#pragma unroll
        for (int k = 0; k < 64; ++k) acc += rowl[r][k] * ws[k * 64 + lane];
        float val = fmaxf(acc, 0.f) * freg;
#pragma unroll
        for (int o = 32; o > 0; o >>= 1) val += __shfl_xor(val, o, 64);
        if (lane == 0) dots[v] = val;
    }
}

// pooled accumulation: LDS-binned segmented reduce over sorted batch.
__global__ __launch_bounds__(256) void k_pool(int n, const float* __restrict__ dots,
                                              const int* __restrict__ batch,
                                              float* __restrict__ gsum,
                                              float* __restrict__ gcnt) {
    __shared__ float ls[64], lc[64];
    __shared__ int gmin_s;
    int tid = threadIdx.x;
    int i0 = blockIdx.x * 1024;
    if (tid == 0) gmin_s = batch[i0];
    if (tid < 64) { ls[tid] = 0.f; lc[tid] = 0.f; }
    __syncthreads();
    int gmin = gmin_s;
#pragma unroll
    for (int c = 0; c < 4; ++c) {
        int i = i0 + c * 256 + tid;
        if (i < n) {
            int g = batch[i];
            float d = dots[i];
            int rr = g - gmin;
            if (rr < 64) {
                atomicAdd(&ls[rr], d);
                atomicAdd(&lc[rr], 1.f);
            } else {
                atomicAdd(&gsum[g], d);
                atomicAdd(&gcnt[g], 1.f);
            }
        }
    }
    __syncthreads();
    if (tid < 64 && lc[tid] != 0.f) {
        atomicAdd(&gsum[gmin + tid], ls[tid]);
        atomicAdd(&gcnt[gmin + tid], lc[tid]);
    }
}

__global__ __launch_bounds__(256) void k_out(int g, const float* __restrict__ gsum,
                                             const float* __restrict__ gcnt,
                                             const float* __restrict__ fcb,
                                             float* __restrict__ out) {
    int i = blockIdx.x * blockDim.x + threadIdx.x;
    if (i < g) out[i] = gsum[i] / fmaxf(gcnt[i], 1.f) + fcb[0];
}

extern "C" void kernel_launch(void* const* d_in, const int* in_sizes, int n_in,
                              void* d_out, int out_size, void* d_ws, size_t ws_size,
                              hipStream_t stream) {
    const float* x    = (const float*)d_in[0];
    const int*   ei   = (const int*)d_in[1];
    const int*   batch= (const int*)d_in[2];
    const float* w1   = (const float*)d_in[3];
    const float* b1   = (const float*)d_in[4];
    const float* w2   = (const float*)d_in[5];
    const float* b2   = (const float*)d_in[6];
    const float* w3   = (const float*)d_in[7];
    const float* b3   = (const float*)d_in[8];
    const float* fcw  = (const float*)d_in[9];
    const float* fcb  = (const float*)d_in[10];
    float* out = (float*)d_out;

    const int N = in_sizes[0];
    const int E = in_sizes[1] / 2;
    const int G = out_size;
    const int H = 64;
    const int SC = (N + NCHUNK - 1) / NCHUNK;   // src-chunk size
    const int n16 = N * NCHUNK;

    const int* src = ei;
    const int* dst = ei + E;

    char* p = (char*)d_ws;
    int*   starts16 = (int*)p; p += WS_ALIGN(sizeof(int) * (size_t)(n16 + 1));  // counts, scanned in place
    int*   cursor16 = (int*)p; p += WS_ALIGN(sizeof(int) * (size_t)n16);
    int*   psum     = (int*)p; p += WS_ALIGN(sizeof(int) * 1024);
    int*   csr      = (int*)p; p += WS_ALIGN(sizeof(int) * (size_t)E);
    float* dinv     = (float*)p; p += WS_ALIGN(sizeof(float) * N);
    float* xs       = (float*)p; p += WS_ALIGN(sizeof(float) * N);
    float* bufA     = (float*)p; p += WS_ALIGN(sizeof(float) * (size_t)N * H);
    float* bufB     = (float*)p; p += WS_ALIGN(sizeof(float) * (size_t)N * H);
    float* dots     = (float*)p; p += WS_ALIGN(sizeof(float) * N);
    float* gsum     = (float*)p; p += WS_ALIGN(sizeof(float) * G);
    float* gcnt     = (float*)p; p += WS_ALIGN(sizeof(float) * G);

    const int B = 256;
    int gridN    = (N + B - 1) / B;
    int gridE    = (E + B - 1) / B;
    int gridG    = (G + B - 1) / B;
    int grid16   = (n16 + B - 1) / B;
    int nscan    = (n16 + 2047) / 2048;          // scan1 blocks (<=1024)
    int gridS3   = (n16 + 1 + B - 1) / B;
    int gridGa   = (N + NB - 1) / NB;            // 2041 persistent-resident blocks
    int gridPool = (N + 1023) / 1024;
    int gridPers = 2048;
    if (gridPers * 4 > N) gridPers = (N + 3) / 4;

    k_init0<<<grid16, B, 0, stream>>>(n16, G, starts16, cursor16, gsum, gcnt);
    k_cnt<<<gridE, B, 0, stream>>>(E, SC, src, dst, starts16);
    k_scan1<<<nscan, B, 0, stream>>>(n16, starts16, starts16, psum);
    k_scan2<<<1, B, 0, stream>>>(nscan, psum);
    k_scan3<<<gridS3, B, 0, stream>>>(n16, E, starts16, psum);
    k_dinv<<<gridN, B, 0, stream>>>(N, starts16, x, dinv, xs);
    k_scatter<<<gridE, B, 0, stream>>>(E, SC, src, dst, starts16, cursor16, csr);
    // layer 1 (rank-1, fused)
    k_layer1<<<gridPers, B, 0, stream>>>(N, starts16, csr, xs, dinv, w1, b1, bufA);
    // layer 2
    k_gather_c<<<gridGa, B, 0, stream>>>(N, starts16, csr, bufA, dinv, bufB);
    k_gemm_mid<<<gridPers, B, 0, stream>>>(N, bufB, w2, b2, dinv, bufA);
    // layer 3
    k_gather_c<<<gridGa, B, 0, stream>>>(N, starts16, csr, bufA, dinv, bufB);
    k_gemm_final<<<gridPers, B, 0, stream>>>(N, bufB, w3, b3, fcw, dots);
    // pooling + head
    k_pool<<<gridPool, B, 0, stream>>>(N, dots, batch, gsum, gcnt);
    k_out<<<gridG, B, 0, stream>>>(G, gsum, gcnt, fcb, out);
}